// Round 5
// baseline (380.509 us; speedup 1.0000x reference)
//
#include <hip/hip_runtime.h>

// Problem constants
#define B_    64
#define IN_   1024
#define OUT_  1024
#define NROWS 65536
#define NBLK  4096      // k_main grid

// ---------- math constants ----------
#define LOG2E_F 1.4426950408889634f
#define LN2_F   0.6931471805599453f
#define LN2_D   0.6931471805599453
#define LSQ2PI_D 0.9189385332046727
// log2-domain mixture constants:
#define CA2_D  (-2.3257480647361595)
#define CA2_F  (-2.3257481f)
#define A1_2_D (-0.7213475204444817)
#define A1_2_F (-0.72134752f)
#define NDS2_F (-180336.159f)
#define NDC2_F (8.965784284662087f)

typedef float f32x4 __attribute__((ext_vector_type(4)));

__device__ __forceinline__ f32x4 ntld(const f32x4* p) {
    return __builtin_nontemporal_load(p);
}
__device__ __forceinline__ float fexp2(float x) {
    return __builtin_amdgcn_exp2f(x);
}
__device__ __forceinline__ float flog2(float x) {
    return __builtin_amdgcn_logf(x);
}
__device__ __forceinline__ float softterm(float t) {  // log2(1+2^t)
    return flog2(1.0f + fexp2(t));
}
__device__ __forceinline__ float softplusf(float r) {
    return LN2_F * softterm(r * LOG2E_F);
}

// fused per-element work (weights)
#define COMP(EC, XC, SGC, MUC, DOT)                                           \
    {                                                                         \
        float w  = fmaf(SGC, EC, MUC);                                        \
        DOT      = fmaf(w, XC, DOT);                                          \
        float v2 = w * w;                                                     \
        sw2 += v2;                                                            \
        soft += softterm(fmaf(NDS2_F, v2, NDC2_F));                           \
        ep2 = fmaf(EC, EC, ep2);                                              \
    }

__global__ __launch_bounds__(256, 3) void k_main(const float* __restrict__ x,
                                                 const float* __restrict__ wmu,
                                                 const float* __restrict__ wrho,
                                                 const float* __restrict__ bmu,
                                                 const float* __restrict__ brho,
                                                 const float* __restrict__ epsw,
                                                 const float* __restrict__ epsb,
                                                 float* __restrict__ out,
                                                 float* __restrict__ ws) {
    const int lane = threadIdx.x & 63;
    const int wid  = threadIdx.x >> 6;
    const int gw   = blockIdx.x * 4 + wid;  // 0..16383
    const int o    = gw & 1023;             // output column (fixed per wave)
    const int b0   = gw >> 10;              // 0..15

    // ---- 1. issue ALL 16 eps loads first: 16 KB per wave in flight ----
    f32x4 e[4][4];
#pragma unroll
    for (int j = 0; j < 4; ++j) {
        const size_t bb = (size_t)(b0 + 16 * j);
        const f32x4* ep = (const f32x4*)(epsw + (((bb << 10) | (size_t)o) << 10));
#pragma unroll
        for (int k = 0; k < 4; ++k) e[j][k] = ntld(ep + lane + 64 * k);
    }

    // ---- 2. sigma/mu hoist for this o (latency of eps hides under this) ----
    const f32x4* mp = (const f32x4*)(wmu  + (size_t)o * IN_);
    const f32x4* rp = (const f32x4*)(wrho + (size_t)o * IN_);
    f32x4 sg[4], mu[4];
#pragma unroll
    for (int k = 0; k < 4; ++k) {
        f32x4 r = rp[lane + 64 * k];
        mu[k]   = mp[lane + 64 * k];
        sg[k].x = softplusf(r.x);
        sg[k].y = softplusf(r.y);
        sg[k].z = softplusf(r.z);
        sg[k].w = softplusf(r.w);
    }

    // sum log2(sigma) over this o-row, once per o (b0==0 waves only)
    float lsg = 0.f;
    if (b0 == 0) {
#pragma unroll
        for (int k = 0; k < 4; ++k)
            lsg += flog2(sg[k].x) + flog2(sg[k].y) + flog2(sg[k].z) + flog2(sg[k].w);
    }

    // bias hoist (wave-uniform o)
    float sgb   = softplusf(brho[o]);
    float l2sgb = flog2(sgb);
    float bm    = bmu[o];

    // ---- 3. compute: consume eps in issue order, lazy L2-hot x loads ----
    float dot0 = 0.f, dot1 = 0.f, dot2 = 0.f, dot3 = 0.f;
    float soft = 0.f, sw2 = 0.f, ep2 = 0.f;

#define ROWJ(J, DOT)                                                          \
    {                                                                         \
        const f32x4* xp = (const f32x4*)(x + ((size_t)(b0 + 16 * (J)) << 10));\
        _Pragma("unroll")                                                     \
        for (int k = 0; k < 4; ++k) {                                         \
            f32x4 xx = xp[lane + 64 * k];                                     \
            COMP(e[J][k].x, xx.x, sg[k].x, mu[k].x, DOT)                      \
            COMP(e[J][k].y, xx.y, sg[k].y, mu[k].y, DOT)                      \
            COMP(e[J][k].z, xx.z, sg[k].z, mu[k].z, DOT)                      \
            COMP(e[J][k].w, xx.w, sg[k].w, mu[k].w, DOT)                      \
        }                                                                     \
    }
    ROWJ(0, dot0)
    ROWJ(1, dot1)
    ROWJ(2, dot2)
    ROWJ(3, dot3)
#undef ROWJ

    // bias per row: lanes 0..3 own rows b0+16*lane
    float bv = 0.f, pb2 = 0.f, postb = 0.f;
    const int bb = b0 + 16 * lane;
    if (lane < 4) {
        float eb  = epsb[((size_t)bb << 10) | (size_t)o];
        bv        = fmaf(sgb, eb, bm);
        float v2b = bv * bv;
        pb2   = fmaf(A1_2_F, v2b, CA2_F) + softterm(fmaf(NDS2_F, v2b, NDC2_F));
        postb = fmaf(-LN2_F, l2sgb, -0.5f * eb * eb);
    }

    // one interleaved butterfly for all 10 values (ILP across chains)
#pragma unroll
    for (int off = 32; off; off >>= 1) {
        dot0 += __shfl_xor(dot0, off, 64);
        dot1 += __shfl_xor(dot1, off, 64);
        dot2 += __shfl_xor(dot2, off, 64);
        dot3 += __shfl_xor(dot3, off, 64);
        soft += __shfl_xor(soft, off, 64);
        sw2  += __shfl_xor(sw2,  off, 64);
        ep2  += __shfl_xor(ep2,  off, 64);
        lsg  += __shfl_xor(lsg,  off, 64);
        pb2  += __shfl_xor(pb2,  off, 64);
        postb+= __shfl_xor(postb,off, 64);
    }

    if (lane < 4) {
        float d = (lane == 0) ? dot0 : (lane == 1) ? dot1 : (lane == 2) ? dot2 : dot3;
        out[((size_t)bb << 10) | (size_t)o] = d + bv;
    }

    // block combine -> per-block slots in ws (slot-major for coalesced k_fin)
    __shared__ float sm[6][4];
    if (lane == 0) {
        sm[0][wid] = soft;
        sm[1][wid] = ep2;
        sm[2][wid] = sw2;
        sm[3][wid] = pb2;
        sm[4][wid] = postb;
        sm[5][wid] = lsg;   // zero for b0!=0 waves
    }
    __syncthreads();
    if (threadIdx.x < 6) {
        int s = threadIdx.x;
        ws[s * NBLK + blockIdx.x] = sm[s][0] + sm[s][1] + sm[s][2] + sm[s][3];
    }
}

__global__ __launch_bounds__(1024) void k_fin(const float* __restrict__ ws,
                                              float* __restrict__ out) {
    const int t    = threadIdx.x;
    const int lane = t & 63;
    const int wid  = t >> 6;   // 0..15
    double a[6] = {0, 0, 0, 0, 0, 0};
#pragma unroll
    for (int i = 0; i < 4; ++i) {
        int idx = t + 1024 * i;
#pragma unroll
        for (int s = 0; s < 6; ++s) a[s] += (double)ws[s * NBLK + idx];
    }
#pragma unroll
    for (int off = 32; off; off >>= 1) {
#pragma unroll
        for (int s = 0; s < 6; ++s) a[s] += __shfl_xor(a[s], off, 64);
    }
    __shared__ double sm[6][16];
    if (lane == 0) {
#pragma unroll
        for (int s = 0; s < 6; ++s) sm[s][wid] = a[s];
    }
    __syncthreads();
    if (t == 0) {
        double v[6];
#pragma unroll
        for (int s = 0; s < 6; ++s) {
            double acc = 0.0;
            for (int w = 0; w < 16; ++w) acc += sm[s][w];
            v[s] = acc;
        }
        double soft2 = v[0], eps2 = v[1], sw2 = v[2];
        double p2b = v[3], postb = v[4], lsig2 = v[5];
        const double NW = 67108864.0;  // B*OUT*IN
        double log_prior = LN2_D * (soft2 + A1_2_D * sw2 + NW * CA2_D + p2b);
        double log_post  = -NW * LSQ2PI_D - 64.0 * (LN2_D * lsig2) - 0.5 * eps2
                           + postb - 65536.0 * LSQ2PI_D;
        out[NROWS]     = (float)log_prior;
        out[NROWS + 1] = (float)log_post;
    }
}

extern "C" void kernel_launch(void* const* d_in, const int* in_sizes, int n_in,
                              void* d_out, int out_size, void* d_ws, size_t ws_size,
                              hipStream_t stream) {
    const float* x    = (const float*)d_in[0];
    const float* wmu  = (const float*)d_in[1];
    const float* wrho = (const float*)d_in[2];
    const float* bmu  = (const float*)d_in[3];
    const float* brho = (const float*)d_in[4];
    const float* epsw = (const float*)d_in[5];
    const float* epsb = (const float*)d_in[6];
    float* out = (float*)d_out;
    float* ws  = (float*)d_ws;

    k_main<<<NBLK, 256, 0, stream>>>(x, wmu, wrho, bmu, brho, epsw, epsb, out, ws);
    k_fin<<<1, 1024, 0, stream>>>(ws, out);
}